// Round 19
// baseline (138.634 us; speedup 1.0000x reference)
//
#include <hip/hip_runtime.h>
#include <stdint.h>
#include <stddef.h>

typedef __bf16 bf16x8 __attribute__((ext_vector_type(8)));
typedef float  f32x4  __attribute__((ext_vector_type(4)));
typedef unsigned u32x4 __attribute__((ext_vector_type(4)));

constexpr int BB  = 2;
constexpr int SS  = 2048;
constexpr int DD  = 1024;
constexpr int HH  = 16;
constexpr int DHD = 64;
constexpr int BHD = BB * HH;     // 32
constexpr int MTOK = BB * SS;    // 4096

__device__ __forceinline__ short f2bf(float f) {
  return (short)__builtin_bit_cast(unsigned short, (__bf16)f);
}
__device__ __forceinline__ uint32_t pk2bf(float a, float b) {
  uint32_t lo = __builtin_bit_cast(unsigned short, (__bf16)a);
  uint32_t hi = __builtin_bit_cast(unsigned short, (__bf16)b);
  return lo | (hi << 16);
}
__device__ __forceinline__ f32x4 mfma16(bf16x8 a, bf16x8 b, f32x4 c) {
  return __builtin_amdgcn_mfma_f32_16x16x32_bf16(a, b, c, 0, 0, 0);
}
__device__ __forceinline__ void gload16(const void* g, void* l) {
  __builtin_amdgcn_global_load_lds(
      (const __attribute__((address_space(1))) unsigned int*)g,
      (__attribute__((address_space(3))) unsigned int*)l, 16, 0, 0);
}

// ---------------------------------------------------------------------------
// Prepass: fp32 -> bf16 for the 4 weight matrices only.
// ---------------------------------------------------------------------------
__global__ __launch_bounds__(256)
void cvtw_kernel(const float* __restrict__ wq, const float* __restrict__ wk,
                 const float* __restrict__ wv, const float* __restrict__ wo,
                 short* __restrict__ dwq, short* __restrict__ dwk,
                 short* __restrict__ dwv, short* __restrict__ dwo)
{
  constexpr int n4w = 1 << 18;            // 256K float4 per W
  constexpr int total = 4 * n4w;
  int i = blockIdx.x * 256 + threadIdx.x;
  for (; i < total; i += gridDim.x * 256) {
    int sg = i >> 18, off = i & (n4w - 1);
    const float* s = sg == 0 ? wq : sg == 1 ? wk : sg == 2 ? wv : wo;
    short* d       = sg == 0 ? dwq : sg == 1 ? dwk : sg == 2 ? dwv : dwo;
    float4 x = ((const float4*)s)[off];
    uint2 o;
    o.x = pk2bf(x.x, x.y);
    o.y = pk2bf(x.z, x.w);
    ((uint2*)d)[off] = o;
  }
}

constexpr float QSCALE = 0.18033688011112042f;  // 0.125 * log2(e)

// ---------------------------------------------------------------------------
// Fused QKV GEMM: C = (A_fp32 @ W_bf16^T + bias) * oscale.
// m97 structure, mixed staging: B via global_load_lds (proven); A staged
// fp32->bf16 in registers with PREFETCH DEPTH 2 (r18's depth-1 exposed
// ~700cy of HBM latency per K-step: issue->commit gap was one MFMA phase
// ~200cy < 900cy HBM miss). Two named register sets, 2x-unrolled loop
// (static indexing, rule #20). pk2bf rounding == old cvt prepass.
// ---------------------------------------------------------------------------
__global__ __launch_bounds__(256)
void qkv_kernel(const float* __restrict__ q, const float* __restrict__ k,
                const float* __restrict__ v,
                const short* __restrict__ wq16, const short* __restrict__ wk16,
                const short* __restrict__ wv16,
                const float* __restrict__ bq, const float* __restrict__ bk,
                const float* __restrict__ bv,
                short* __restrict__ qh, short* __restrict__ kh,
                short* __restrict__ vt)
{
  const int z = blockIdx.z;
  const float* A = (z == 0) ? q : (z == 1) ? k : v;
  const short* W = (z == 0) ? wq16 : (z == 1) ? wk16 : wv16;
  const float* bias = (z == 0) ? bq : (z == 1) ? bk : bv;
  short* Cp = (z == 0) ? qh : (z == 1) ? kh : vt;
  const int mode = (z == 2) ? 2 : 0;
  const float oscale = (z == 0) ? QSCALE : 1.0f;
  const int m0 = blockIdx.x * 128, n0 = blockIdx.y * 128;

  __shared__ short As[128 * 32];
  __shared__ short Bs[128 * 32];
  const int t = threadIdx.x, lane = t & 63, w = t >> 6;
  const int wr = w >> 1, wc = w & 1, g = lane >> 4, l15 = lane & 15;

  f32x4 acc[4][4] = {};

  // B staging (bf16, gload_lds)
  const int c0 = t, c1 = 256 + t;
  const short* gb0 = W + (size_t)(n0 + (c0 >> 2)) * 1024 + ((c0 & 3) << 3);
  const short* gb1 = W + (size_t)(n0 + (c1 >> 2)) * 1024 + ((c1 & 3) << 3);
  short* lb0 = &Bs[(w * 64) * 8];
  short* lb1 = &Bs[(256 + w * 64) * 8];

  // A staging: chunk c = j*256 + t -> row = c>>3, col = (c&7)*4 fp32
  const float* ga[4];
  #pragma unroll
  for (int j = 0; j < 4; ++j) {
    int c = j * 256 + t;
    ga[j] = A + (size_t)(m0 + (c >> 3)) * 1024 + ((c & 7) << 2);
  }
  float4 aA[4], aB[4];                     // two in-flight sets (depth 2)
  auto issueA = [&](float4* ar, int k0) {
    #pragma unroll
    for (int j = 0; j < 4; ++j) ar[j] = *(const float4*)(ga[j] + k0);
  };
  auto commitA = [&](const float4* ar) {
    #pragma unroll
    for (int j = 0; j < 4; ++j) {
      int c = j * 256 + t;
      uint2 o;
      o.x = pk2bf(ar[j].x, ar[j].y);
      o.y = pk2bf(ar[j].z, ar[j].w);
      *(uint2*)&As[(c >> 3) * 32 + ((c & 7) << 2)] = o;
    }
  };
  auto compute = [&]() {
    bf16x8 af[4], bfr[4];
    #pragma unroll
    for (int m = 0; m < 4; ++m)
      af[m] = *(const bf16x8*)&As[(wr * 64 + m * 16 + l15) * 32 + g * 8];
    #pragma unroll
    for (int n = 0; n < 4; ++n)
      bfr[n] = *(const bf16x8*)&Bs[(wc * 64 + n * 16 + l15) * 32 + g * 8];
    #pragma unroll
    for (int m = 0; m < 4; ++m)
      #pragma unroll
      for (int n = 0; n < 4; ++n)
        acc[m][n] = mfma16(af[m], bfr[n], acc[m][n]);
  };

  issueA(aA, 0);
  issueA(aB, 32);
  for (int tt = 0; tt < 32; tt += 2) {
    // even step: consume aA
    __syncthreads();
    commitA(aA);                           // waits on loads issued 2 steps ago
    gload16(gb0 + tt * 32, lb0);
    gload16(gb1 + tt * 32, lb1);
    __syncthreads();
    if (tt + 2 < 32) issueA(aA, (tt + 2) * 32);   // ~2 full steps ahead
    compute();
    // odd step: consume aB
    __syncthreads();
    commitA(aB);
    gload16(gb0 + (tt + 1) * 32, lb0);
    gload16(gb1 + (tt + 1) * 32, lb1);
    __syncthreads();
    if (tt + 3 < 32) issueA(aB, (tt + 3) * 32);
    compute();
  }

  // C/D: col = lane&15, row = (lane>>4)*4 + reg  [m89]
  #pragma unroll
  for (int n = 0; n < 4; ++n) {
    int ng = n0 + wc * 64 + n * 16 + l15;
    float bv = bias[ng];
    #pragma unroll
    for (int m = 0; m < 4; ++m) {
      int mb = m0 + wr * 64 + m * 16 + g * 4;
      #pragma unroll
      for (int r = 0; r < 4; ++r) {
        int mg = mb + r;
        float val = (acc[m][n][r] + bv) * oscale;
        int b = mg >> 11, srow = mg & 2047;
        int h = ng >> 6,  dh   = ng & 63;
        if (mode == 0)
          ((short*)Cp)[(((size_t)b * HH + h) * SS + srow) * DHD + dh] = f2bf(val);
        else
          ((short*)Cp)[(((size_t)b * HH + h) * DHD + dh) * SS + srow] = f2bf(val);
      }
    }
  }
}

// ---------------------------------------------------------------------------
// Output projection: m97-structure GEMM (all-bf16, single-buffered).
// ---------------------------------------------------------------------------
__global__ __launch_bounds__(256)
void proj_kernel(const short* __restrict__ ao, const short* __restrict__ wo16,
                 const float* __restrict__ bo, float* __restrict__ out)
{
  const int m0 = blockIdx.x * 128, n0 = blockIdx.y * 128;
  __shared__ short As[128 * 32];
  __shared__ short Bs[128 * 32];
  const int t = threadIdx.x, lane = t & 63, w = t >> 6;
  const int wr = w >> 1, wc = w & 1, g = lane >> 4, l15 = lane & 15;

  f32x4 acc[4][4] = {};

  const int c0 = t, c1 = 256 + t;
  const short* ga0 = ao + (size_t)(m0 + (c0 >> 2)) * 1024 + ((c0 & 3) << 3);
  const short* ga1 = ao + (size_t)(m0 + (c1 >> 2)) * 1024 + ((c1 & 3) << 3);
  const short* gb0 = wo16 + (size_t)(n0 + (c0 >> 2)) * 1024 + ((c0 & 3) << 3);
  const short* gb1 = wo16 + (size_t)(n0 + (c1 >> 2)) * 1024 + ((c1 & 3) << 3);
  short* la0 = &As[(w * 64) * 8];
  short* la1 = &As[(256 + w * 64) * 8];
  short* lb0 = &Bs[(w * 64) * 8];
  short* lb1 = &Bs[(256 + w * 64) * 8];

  for (int k0 = 0; k0 < 1024; k0 += 32) {
    __syncthreads();
    gload16(ga0 + k0, la0);
    gload16(ga1 + k0, la1);
    gload16(gb0 + k0, lb0);
    gload16(gb1 + k0, lb1);
    __syncthreads();

    bf16x8 af[4], bfr[4];
    #pragma unroll
    for (int m = 0; m < 4; ++m)
      af[m] = *(const bf16x8*)&As[(wr * 64 + m * 16 + l15) * 32 + g * 8];
    #pragma unroll
    for (int n = 0; n < 4; ++n)
      bfr[n] = *(const bf16x8*)&Bs[(wc * 64 + n * 16 + l15) * 32 + g * 8];
    #pragma unroll
    for (int m = 0; m < 4; ++m)
      #pragma unroll
      for (int n = 0; n < 4; ++n)
        acc[m][n] = mfma16(af[m], bfr[n], acc[m][n]);
  }

  #pragma unroll
  for (int n = 0; n < 4; ++n) {
    int ng = n0 + wc * 64 + n * 16 + l15;
    float bv = bo[ng];
    #pragma unroll
    for (int m = 0; m < 4; ++m) {
      int mb = m0 + wr * 64 + m * 16 + g * 4;
      #pragma unroll
      for (int r = 0; r < 4; ++r)
        out[(size_t)(mb + r) * 1024 + ng] = acc[m][n][r] + bv;
    }
  }
}

// ---------------------------------------------------------------------------
// Flash attention (r15 verbatim - best measured, 48.0us): sequential paired
// q-tiles, uniform 17 staged-tile units/block, 512 blocks, swapped QK,
// no-max exp2 softmax, permlane P-transpose, XOR-swizzled staging.
// ---------------------------------------------------------------------------
__global__ __launch_bounds__(256)
void attn_kernel(const short* __restrict__ qh, const short* __restrict__ kh,
                 const short* __restrict__ vt, short* __restrict__ out)
{
  __shared__ short Ks[128 * 64];     // [kv=128][d=64], swz byte^=(row&7)<<4
  __shared__ short Vs[64 * 128];     // [d=64][kv=128], swz byte^=(row&15)<<4

  const int wg = blockIdx.x;
  const int s  = wg >> 3;
  const int bh = (wg & 7) * 4 + (s & 3);      // 4 heads per XCD
  const int p  = s >> 2;                      // pair index 0..15

  const int t = threadIdx.x, lane = t & 63, w = t >> 6;
  const int g = lane >> 4, l15 = lane & 15;
  const int b = bh >> 4, h = bh & 15;

  const short* kbh = kh + (size_t)bh * SS * DHD;
  const short* vbh = vt + (size_t)bh * DHD * SS;

  bf16x8 kr[4], vr[4];
  auto issue = [&](int k0) {
    #pragma unroll
    for (int j = 0; j < 4; ++j) {
      int c = j * 256 + t;
      kr[j] = *(const bf16x8*)(kbh + (size_t)(k0 + (c >> 3)) * DHD + ((c & 7) << 3));
      vr[j] = *(const bf16x8*)(vbh + (size_t)(c >> 4) * SS + k0 + ((c & 15) << 3));
    }
  };
  auto commit = [&]() {
    #pragma unroll
    for (int j = 0; j < 4; ++j) {
      int c = j * 256 + t;
      int kb_ = ((c >> 3) * 128 + (c & 7) * 16) ^ (((c >> 3) & 7) << 4);
      int vb_ = ((c >> 4) * 256 + (c & 15) * 16) ^ (((c >> 4) & 15) << 4);
      *(bf16x8*)((char*)Ks + kb_) = kr[j];
      *(bf16x8*)((char*)Vs + vb_) = vr[j];
    }
  };

  #pragma unroll 1
  for (int ph = 0; ph < 2; ++ph) {
    const int y = ph ? (31 - p) : p;
    const int ktiles = (y + 2) >> 1;          // 128-wide kv tiles

    const short* qp = qh + ((size_t)bh * SS + y * 64 + w * 16 + l15) * DHD + g * 8;
    bf16x8 q0f = *(const bf16x8*)(qp);
    bf16x8 q1f = *(const bf16x8*)(qp + 32);

    f32x4 o[4] = {};
    f32x4 lv = {0.f, 0.f, 0.f, 0.f};
    const int qg = y * 64 + w * 16 + l15;

    issue(0);
    for (int kt = 0; kt < ktiles; ++kt) {
      const int k0 = kt * 128;
      __syncthreads();                // prev compute done, buffers free
      commit();                       // vmcnt wait + swizzled ds_write
      __syncthreads();                // tile staged
      if (kt + 1 < ktiles) issue(k0 + 128);  // next tile flies under compute

      f32x4 s4[8];
      __builtin_amdgcn_s_setprio(1);
      #pragma unroll
      for (int nk = 0; nk < 8; ++nk) {
        int row = nk * 16 + l15;
        int sw = (row & 7) << 4;
        bf16x8 kf0 = *(const bf16x8*)((const char*)Ks + ((row * 128 + g * 16) ^ sw));
        bf16x8 kf1 = *(const bf16x8*)((const char*)Ks + ((row * 128 + 64 + g * 16) ^ sw));
        f32x4 z = {0.f, 0.f, 0.f, 0.f};
        z = mfma16(kf0, q0f, z);
        s4[nk] = mfma16(kf1, q1f, z);
      }
      __builtin_amdgcn_s_setprio(0);
      if (kt == ktiles - 1) {         // only the last tile crosses the diagonal
        #pragma unroll
        for (int nk = 0; nk < 8; ++nk)
          #pragma unroll
          for (int r = 0; r < 4; ++r)
            if (k0 + nk * 16 + g * 4 + r > qg) s4[nk][r] = -__builtin_inff();
      }
      #pragma unroll
      for (int nk = 0; nk < 8; ++nk) {
        #pragma unroll
        for (int r = 0; r < 4; ++r) s4[nk][r] = exp2f(s4[nk][r]);
        lv += s4[nk];
      }
      __builtin_amdgcn_s_setprio(1);
      #pragma unroll
      for (int i = 0; i < 4; ++i) {
        uint32_t w0 = pk2bf(s4[2 * i][0], s4[2 * i][1]);
        uint32_t w1 = pk2bf(s4[2 * i][2], s4[2 * i][3]);
        uint32_t w2 = pk2bf(s4[2 * i + 1][0], s4[2 * i + 1][1]);
        uint32_t w3 = pk2bf(s4[2 * i + 1][2], s4[2 * i + 1][3]);
        auto p1 = __builtin_amdgcn_permlane32_swap(w0, w2, false, false);
        auto p2 = __builtin_amdgcn_permlane16_swap(p1[0], p1[1], false, false);
        auto p3 = __builtin_amdgcn_permlane32_swap(w1, w3, false, false);
        auto p4 = __builtin_amdgcn_permlane16_swap(p3[0], p3[1], false, false);
        u32x4 paw = {(unsigned)p2[0], (unsigned)p4[0],
                     (unsigned)p2[1], (unsigned)p4[1]};
        bf16x8 pa = __builtin_bit_cast(bf16x8, paw);
        #pragma unroll
        for (int nd = 0; nd < 4; ++nd) {
          int row = nd * 16 + l15;
          int byt = (row * 256 + i * 64 + g * 16) ^ ((row & 15) << 4);
          bf16x8 vf = *(const bf16x8*)((const char*)Vs + byt);
          o[nd] = mfma16(pa, vf, o[nd]);
        }
      }
      __builtin_amdgcn_s_setprio(0);
    }

    float l = (lv[0] + lv[1]) + (lv[2] + lv[3]);
    l += __shfl_xor(l, 16, 64);
    l += __shfl_xor(l, 32, 64);
    #pragma unroll
    for (int r = 0; r < 4; ++r) {
      float lr = __shfl(l, g * 4 + r, 64);
      float inv = 1.0f / lr;
      int srow = y * 64 + w * 16 + g * 4 + r;
      #pragma unroll
      for (int nd = 0; nd < 4; ++nd) {
        int dcol = h * 64 + nd * 16 + l15;
        out[((size_t)b * SS + srow) * DD + dcol] = f2bf(o[nd][r] * inv);
      }
    }
  }
}

// ---------------------------------------------------------------------------
extern "C" void kernel_launch(void* const* d_in, const int* in_sizes, int n_in,
                              void* d_out, int out_size, void* d_ws, size_t ws_size,
                              hipStream_t stream) {
  (void)in_sizes; (void)n_in; (void)out_size; (void)ws_size;
  const float* q  = (const float*)d_in[0];
  const float* k  = (const float*)d_in[1];
  const float* v  = (const float*)d_in[2];
  // d_in[3] = causal mask (statically triu(k=1)) applied analytically
  const float* Wq = (const float*)d_in[4];
  const float* bq = (const float*)d_in[5];
  const float* Wk = (const float*)d_in[6];
  const float* bk = (const float*)d_in[7];
  const float* Wv = (const float*)d_in[8];
  const float* bv = (const float*)d_in[9];
  const float* Wo = (const float*)d_in[10];
  const float* bo = (const float*)d_in[11];

  constexpr size_t NTOK = (size_t)MTOK * DD;     // 4M elements
  constexpr size_t NW   = (size_t)DD * DD;       // 1M elements
  short* wq16 = (short*)d_ws;                    // [1024,1024] bf16 x4
  short* wk16 = wq16 + NW;
  short* wv16 = wk16 + NW;
  short* wo16 = wv16 + NW;
  short* qh   = wo16 + NW;                       // [B,H,S,DH] bf16 (pre-scaled)
  short* kh   = qh + NTOK;                       // [B,H,S,DH] bf16
  short* vt   = kh + NTOK;                       // [B,H,DH,S] bf16
  short* ao   = vt + NTOK;                       // [B,S,D]   bf16

  dim3 blk(256);
  cvtw_kernel<<<dim3(512), blk, 0, stream>>>(Wq, Wk, Wv, Wo,
                                             wq16, wk16, wv16, wo16);
  qkv_kernel<<<dim3(MTOK / 128, DD / 128, 3), blk, 0, stream>>>(
      q, k, v, wq16, wk16, wv16, bq, bk, bv, qh, kh, vt);
  attn_kernel<<<dim3(512), blk, 0, stream>>>(qh, kh, vt, ao);
  proj_kernel<<<dim3(MTOK / 128, DD / 128), blk, 0, stream>>>(ao, wo16, bo,
                                                              (float*)d_out);
}

// Round 20
// 118.554 us; speedup vs baseline: 1.1694x; 1.1694x over previous
//
#include <hip/hip_runtime.h>
#include <stdint.h>
#include <stddef.h>

typedef __bf16 bf16x8 __attribute__((ext_vector_type(8)));
typedef float  f32x4  __attribute__((ext_vector_type(4)));
typedef unsigned u32x4 __attribute__((ext_vector_type(4)));

constexpr int BB  = 2;
constexpr int SS  = 2048;
constexpr int DD  = 1024;
constexpr int HH  = 16;
constexpr int DHD = 64;
constexpr int BHD = BB * HH;     // 32
constexpr int MTOK = BB * SS;    // 4096

__device__ __forceinline__ short f2bf(float f) {
  return (short)__builtin_bit_cast(unsigned short, (__bf16)f);
}
__device__ __forceinline__ uint32_t pk2bf(float a, float b) {
  uint32_t lo = __builtin_bit_cast(unsigned short, (__bf16)a);
  uint32_t hi = __builtin_bit_cast(unsigned short, (__bf16)b);
  return lo | (hi << 16);
}
__device__ __forceinline__ f32x4 mfma16(bf16x8 a, bf16x8 b, f32x4 c) {
  return __builtin_amdgcn_mfma_f32_16x16x32_bf16(a, b, c, 0, 0, 0);
}
__device__ __forceinline__ void gload16(const void* g, void* l) {
  __builtin_amdgcn_global_load_lds(
      (const __attribute__((address_space(1))) unsigned int*)g,
      (__attribute__((address_space(3))) unsigned int*)l, 16, 0, 0);
}

// ---------------------------------------------------------------------------
// Prepass: fp32 -> bf16 for q,k,v and the 4 weight matrices.
// ---------------------------------------------------------------------------
__global__ __launch_bounds__(256)
void cvt_kernel(const float* __restrict__ q, const float* __restrict__ k,
                const float* __restrict__ v,
                const float* __restrict__ wq, const float* __restrict__ wk,
                const float* __restrict__ wv, const float* __restrict__ wo,
                short* __restrict__ dq, short* __restrict__ dk,
                short* __restrict__ dv,
                short* __restrict__ dwq, short* __restrict__ dwk,
                short* __restrict__ dwv, short* __restrict__ dwo)
{
  constexpr int n4q = 1 << 20;
  constexpr int n4w = 1 << 18;
  constexpr int total = 3 * n4q + 4 * n4w;
  int i = blockIdx.x * 256 + threadIdx.x;
  for (; i < total; i += gridDim.x * 256) {
    const float* s; short* d; int off;
    if (i < 3 * n4q) {
      int sg = i >> 20; off = i & (n4q - 1);
      s = sg == 0 ? q : sg == 1 ? k : v;
      d = sg == 0 ? dq : sg == 1 ? dk : dv;
    } else {
      int j = i - 3 * n4q;
      int sg = j >> 18; off = j & (n4w - 1);
      s = sg == 0 ? wq : sg == 1 ? wk : sg == 2 ? wv : wo;
      d = sg == 0 ? dwq : sg == 1 ? dwk : sg == 2 ? dwv : dwo;
    }
    float4 x = ((const float4*)s)[off];
    uint2 o;
    o.x = pk2bf(x.x, x.y);
    o.y = pk2bf(x.z, x.w);
    ((uint2*)d)[off] = o;
  }
}

// ---------------------------------------------------------------------------
// m97-structure GEMM (single-buffered - measured best):
// C = (A @ W^T + bias) * oscale. All-bf16, 128x128 tile, BK=32,
// global_load_lds width=16, linear LDS.
// ---------------------------------------------------------------------------
__device__ __forceinline__ void gemm_body(
    const short* __restrict__ A, const short* __restrict__ W,
    const float* __restrict__ bias, void* __restrict__ Cp,
    int mode, float oscale, int m0, int n0)
{
  __shared__ short As[128 * 32];
  __shared__ short Bs[128 * 32];
  const int t = threadIdx.x, lane = t & 63, w = t >> 6;
  const int wr = w >> 1, wc = w & 1, g = lane >> 4, l15 = lane & 15;

  f32x4 acc[4][4] = {};

  const int c0 = t, c1 = 256 + t;
  const short* ga0 = A + (size_t)(m0 + (c0 >> 2)) * 1024 + ((c0 & 3) << 3);
  const short* ga1 = A + (size_t)(m0 + (c1 >> 2)) * 1024 + ((c1 & 3) << 3);
  const short* gb0 = W + (size_t)(n0 + (c0 >> 2)) * 1024 + ((c0 & 3) << 3);
  const short* gb1 = W + (size_t)(n0 + (c1 >> 2)) * 1024 + ((c1 & 3) << 3);
  short* la0 = &As[(w * 64) * 8];
  short* la1 = &As[(256 + w * 64) * 8];
  short* lb0 = &Bs[(w * 64) * 8];
  short* lb1 = &Bs[(256 + w * 64) * 8];

  for (int k0 = 0; k0 < 1024; k0 += 32) {
    __syncthreads();
    gload16(ga0 + k0, la0);
    gload16(ga1 + k0, la1);
    gload16(gb0 + k0, lb0);
    gload16(gb1 + k0, lb1);
    __syncthreads();

    bf16x8 af[4], bfr[4];
    #pragma unroll
    for (int m = 0; m < 4; ++m)
      af[m] = *(const bf16x8*)&As[(wr * 64 + m * 16 + l15) * 32 + g * 8];
    #pragma unroll
    for (int n = 0; n < 4; ++n)
      bfr[n] = *(const bf16x8*)&Bs[(wc * 64 + n * 16 + l15) * 32 + g * 8];
    #pragma unroll
    for (int m = 0; m < 4; ++m)
      #pragma unroll
      for (int n = 0; n < 4; ++n)
        acc[m][n] = mfma16(af[m], bfr[n], acc[m][n]);
  }

  // C/D: col = lane&15, row = (lane>>4)*4 + reg  [m89]
  #pragma unroll
  for (int n = 0; n < 4; ++n) {
    int ng = n0 + wc * 64 + n * 16 + l15;
    float bv = bias[ng];
    #pragma unroll
    for (int m = 0; m < 4; ++m) {
      int mb = m0 + wr * 64 + m * 16 + g * 4;
      #pragma unroll
      for (int r = 0; r < 4; ++r) {
        int mg = mb + r;
        float val = (acc[m][n][r] + bv) * oscale;
        if (mode == 1) {
          ((float*)Cp)[(size_t)mg * 1024 + ng] = val;
        } else {
          int b = mg >> 11, srow = mg & 2047;
          int h = ng >> 6,  dh   = ng & 63;
          if (mode == 0)
            ((short*)Cp)[(((size_t)b * HH + h) * SS + srow) * DHD + dh] = f2bf(val);
          else
            ((short*)Cp)[(((size_t)b * HH + h) * DHD + dh) * SS + srow] = f2bf(val);
        }
      }
    }
  }
}

constexpr float QSCALE = 0.18033688011112042f;  // 0.125 * log2(e)

__global__ __launch_bounds__(256)
void qkv_kernel(const short* __restrict__ qb, const short* __restrict__ kb,
                const short* __restrict__ vb,
                const short* __restrict__ wq16, const short* __restrict__ wk16,
                const short* __restrict__ wv16,
                const float* __restrict__ bq, const float* __restrict__ bk,
                const float* __restrict__ bv,
                short* __restrict__ qh, short* __restrict__ kh,
                short* __restrict__ vt)
{
  const int z = blockIdx.z;
  const short* A = (z == 0) ? qb : (z == 1) ? kb : vb;
  const short* W = (z == 0) ? wq16 : (z == 1) ? wk16 : wv16;
  const float* b = (z == 0) ? bq : (z == 1) ? bk : bv;
  void* C = (z == 0) ? (void*)qh : (z == 1) ? (void*)kh : (void*)vt;
  int mode = (z == 2) ? 2 : 0;
  float sc = (z == 0) ? QSCALE : 1.0f;
  gemm_body(A, W, b, C, mode, sc, blockIdx.x * 128, blockIdx.y * 128);
}

__global__ __launch_bounds__(256)
void proj_kernel(const short* __restrict__ ao, const short* __restrict__ wo16,
                 const float* __restrict__ bo, float* __restrict__ out)
{
  gemm_body(ao, wo16, bo, out, 1, 1.0f, blockIdx.x * 128, blockIdx.y * 128);
}

// ---------------------------------------------------------------------------
// Flash attention v15 (best measured, 48.0us): SEQUENTIAL paired q-tiles.
// Block p processes yA=p fully, then yB=31-p. Every block = exactly 17
// staged-tile units -> zero tail, 512 blocks = 2/CU resident start-to-
// finish. Body: swapped QK (mfma(K,Q)), no-max exp2 softmax, permlane
// P-transpose, XOR-swizzled reg-staged K/V, T5 setprio.
// ---------------------------------------------------------------------------
__global__ __launch_bounds__(256)
void attn_kernel(const short* __restrict__ qh, const short* __restrict__ kh,
                 const short* __restrict__ vt, short* __restrict__ out)
{
  __shared__ short Ks[128 * 64];     // [kv=128][d=64], swz byte^=(row&7)<<4
  __shared__ short Vs[64 * 128];     // [d=64][kv=128], swz byte^=(row&15)<<4

  const int wg = blockIdx.x;
  const int s  = wg >> 3;
  const int bh = (wg & 7) * 4 + (s & 3);      // 4 heads per XCD
  const int p  = s >> 2;                      // pair index 0..15

  const int t = threadIdx.x, lane = t & 63, w = t >> 6;
  const int g = lane >> 4, l15 = lane & 15;
  const int b = bh >> 4, h = bh & 15;

  const short* kbh = kh + (size_t)bh * SS * DHD;
  const short* vbh = vt + (size_t)bh * DHD * SS;

  bf16x8 kr[4], vr[4];
  auto issue = [&](int k0) {
    #pragma unroll
    for (int j = 0; j < 4; ++j) {
      int c = j * 256 + t;
      kr[j] = *(const bf16x8*)(kbh + (size_t)(k0 + (c >> 3)) * DHD + ((c & 7) << 3));
      vr[j] = *(const bf16x8*)(vbh + (size_t)(c >> 4) * SS + k0 + ((c & 15) << 3));
    }
  };
  auto commit = [&]() {
    #pragma unroll
    for (int j = 0; j < 4; ++j) {
      int c = j * 256 + t;
      int kb_ = ((c >> 3) * 128 + (c & 7) * 16) ^ (((c >> 3) & 7) << 4);
      int vb_ = ((c >> 4) * 256 + (c & 15) * 16) ^ (((c >> 4) & 15) << 4);
      *(bf16x8*)((char*)Ks + kb_) = kr[j];
      *(bf16x8*)((char*)Vs + vb_) = vr[j];
    }
  };

  #pragma unroll 1
  for (int ph = 0; ph < 2; ++ph) {
    const int y = ph ? (31 - p) : p;
    const int ktiles = (y + 2) >> 1;          // 128-wide kv tiles

    const short* qp = qh + ((size_t)bh * SS + y * 64 + w * 16 + l15) * DHD + g * 8;
    bf16x8 q0f = *(const bf16x8*)(qp);
    bf16x8 q1f = *(const bf16x8*)(qp + 32);

    f32x4 o[4] = {};
    f32x4 lv = {0.f, 0.f, 0.f, 0.f};
    const int qg = y * 64 + w * 16 + l15;

    issue(0);
    for (int kt = 0; kt < ktiles; ++kt) {
      const int k0 = kt * 128;
      __syncthreads();                // prev compute done, buffers free
      commit();                       // vmcnt wait + swizzled ds_write
      __syncthreads();                // tile staged
      if (kt + 1 < ktiles) issue(k0 + 128);  // next tile flies under compute

      f32x4 s4[8];
      __builtin_amdgcn_s_setprio(1);
      #pragma unroll
      for (int nk = 0; nk < 8; ++nk) {
        int row = nk * 16 + l15;
        int sw = (row & 7) << 4;
        bf16x8 kf0 = *(const bf16x8*)((const char*)Ks + ((row * 128 + g * 16) ^ sw));
        bf16x8 kf1 = *(const bf16x8*)((const char*)Ks + ((row * 128 + 64 + g * 16) ^ sw));
        f32x4 z = {0.f, 0.f, 0.f, 0.f};
        z = mfma16(kf0, q0f, z);
        s4[nk] = mfma16(kf1, q1f, z);
      }
      __builtin_amdgcn_s_setprio(0);
      if (kt == ktiles - 1) {         // only the last tile crosses the diagonal
        #pragma unroll
        for (int nk = 0; nk < 8; ++nk)
          #pragma unroll
          for (int r = 0; r < 4; ++r)
            if (k0 + nk * 16 + g * 4 + r > qg) s4[nk][r] = -__builtin_inff();
      }
      #pragma unroll
      for (int nk = 0; nk < 8; ++nk) {
        #pragma unroll
        for (int r = 0; r < 4; ++r) s4[nk][r] = exp2f(s4[nk][r]);
        lv += s4[nk];
      }
      __builtin_amdgcn_s_setprio(1);
      #pragma unroll
      for (int i = 0; i < 4; ++i) {
        uint32_t w0 = pk2bf(s4[2 * i][0], s4[2 * i][1]);
        uint32_t w1 = pk2bf(s4[2 * i][2], s4[2 * i][3]);
        uint32_t w2 = pk2bf(s4[2 * i + 1][0], s4[2 * i + 1][1]);
        uint32_t w3 = pk2bf(s4[2 * i + 1][2], s4[2 * i + 1][3]);
        auto p1 = __builtin_amdgcn_permlane32_swap(w0, w2, false, false);
        auto p2 = __builtin_amdgcn_permlane16_swap(p1[0], p1[1], false, false);
        auto p3 = __builtin_amdgcn_permlane32_swap(w1, w3, false, false);
        auto p4 = __builtin_amdgcn_permlane16_swap(p3[0], p3[1], false, false);
        u32x4 paw = {(unsigned)p2[0], (unsigned)p4[0],
                     (unsigned)p2[1], (unsigned)p4[1]};
        bf16x8 pa = __builtin_bit_cast(bf16x8, paw);
        #pragma unroll
        for (int nd = 0; nd < 4; ++nd) {
          int row = nd * 16 + l15;
          int byt = (row * 256 + i * 64 + g * 16) ^ ((row & 15) << 4);
          bf16x8 vf = *(const bf16x8*)((const char*)Vs + byt);
          o[nd] = mfma16(pa, vf, o[nd]);
        }
      }
      __builtin_amdgcn_s_setprio(0);
    }

    float l = (lv[0] + lv[1]) + (lv[2] + lv[3]);
    l += __shfl_xor(l, 16, 64);
    l += __shfl_xor(l, 32, 64);
    #pragma unroll
    for (int r = 0; r < 4; ++r) {
      float lr = __shfl(l, g * 4 + r, 64);
      float inv = 1.0f / lr;
      int srow = y * 64 + w * 16 + g * 4 + r;
      #pragma unroll
      for (int nd = 0; nd < 4; ++nd) {
        int dcol = h * 64 + nd * 16 + l15;
        out[((size_t)b * SS + srow) * DD + dcol] = f2bf(o[nd][r] * inv);
      }
    }
  }
}

// ---------------------------------------------------------------------------
extern "C" void kernel_launch(void* const* d_in, const int* in_sizes, int n_in,
                              void* d_out, int out_size, void* d_ws, size_t ws_size,
                              hipStream_t stream) {
  (void)in_sizes; (void)n_in; (void)out_size; (void)ws_size;
  const float* q  = (const float*)d_in[0];
  const float* k  = (const float*)d_in[1];
  const float* v  = (const float*)d_in[2];
  // d_in[3] = causal mask (statically triu(k=1)) applied analytically
  const float* Wq = (const float*)d_in[4];
  const float* bq = (const float*)d_in[5];
  const float* Wk = (const float*)d_in[6];
  const float* bk = (const float*)d_in[7];
  const float* Wv = (const float*)d_in[8];
  const float* bv = (const float*)d_in[9];
  const float* Wo = (const float*)d_in[10];
  const float* bo = (const float*)d_in[11];

  constexpr size_t NTOK = (size_t)MTOK * DD;
  constexpr size_t NW   = (size_t)DD * DD;
  short* qb16 = (short*)d_ws;
  short* kb16 = qb16 + NTOK;
  short* vb16 = kb16 + NTOK;
  short* wq16 = vb16 + NTOK;
  short* wk16 = wq16 + NW;
  short* wv16 = wk16 + NW;
  short* wo16 = wv16 + NW;
  short* qh   = wo16 + NW;                       // [B,H,S,DH] bf16 (pre-scaled)
  short* kh   = qh + NTOK;                       // [B,H,S,DH] bf16
  short* vt   = kh + NTOK;                       // [B,H,DH,S] bf16
  short* ao   = qb16;                            // aliases qb16 (dead by then)

  dim3 blk(256);
  cvt_kernel<<<dim3(2048), blk, 0, stream>>>(q, k, v, Wq, Wk, Wv, Wo,
                                             qb16, kb16, vb16,
                                             wq16, wk16, wv16, wo16);
  qkv_kernel<<<dim3(MTOK / 128, DD / 128, 3), blk, 0, stream>>>(
      qb16, kb16, vb16, wq16, wk16, wv16, bq, bk, bv, qh, kh, vt);
  attn_kernel<<<dim3(512), blk, 0, stream>>>(qh, kh, vt, ao);
  proj_kernel<<<dim3(MTOK / 128, DD / 128), blk, 0, stream>>>(ao, wo16, bo,
                                                              (float*)d_out);
}

// Round 21
// 116.977 us; speedup vs baseline: 1.1851x; 1.0135x over previous
//
#include <hip/hip_runtime.h>
#include <stdint.h>
#include <stddef.h>

typedef __bf16 bf16x8 __attribute__((ext_vector_type(8)));
typedef float  f32x4  __attribute__((ext_vector_type(4)));
typedef unsigned u32x4 __attribute__((ext_vector_type(4)));

constexpr int BB  = 2;
constexpr int SS  = 2048;
constexpr int DD  = 1024;
constexpr int HH  = 16;
constexpr int DHD = 64;
constexpr int BHD = BB * HH;     // 32
constexpr int MTOK = BB * SS;    // 4096

__device__ __forceinline__ short f2bf(float f) {
  return (short)__builtin_bit_cast(unsigned short, (__bf16)f);
}
__device__ __forceinline__ uint32_t pk2bf(float a, float b) {
  uint32_t lo = __builtin_bit_cast(unsigned short, (__bf16)a);
  uint32_t hi = __builtin_bit_cast(unsigned short, (__bf16)b);
  return lo | (hi << 16);
}
__device__ __forceinline__ f32x4 mfma16(bf16x8 a, bf16x8 b, f32x4 c) {
  return __builtin_amdgcn_mfma_f32_16x16x32_bf16(a, b, c, 0, 0, 0);
}
__device__ __forceinline__ void gload16(const void* g, void* l) {
  __builtin_amdgcn_global_load_lds(
      (const __attribute__((address_space(1))) unsigned int*)g,
      (__attribute__((address_space(3))) unsigned int*)l, 16, 0, 0);
}

// ---------------------------------------------------------------------------
// Prepass: fp32 -> bf16 for the 4 weight matrices only (q/k/v stay fp32;
// qkv_kernel converts them on LDS read - saves the 72MB round-trip).
// ---------------------------------------------------------------------------
__global__ __launch_bounds__(256)
void cvtw_kernel(const float* __restrict__ wq, const float* __restrict__ wk,
                 const float* __restrict__ wv, const float* __restrict__ wo,
                 short* __restrict__ dwq, short* __restrict__ dwk,
                 short* __restrict__ dwv, short* __restrict__ dwo)
{
  constexpr int n4w = 1 << 18;            // 256K float4 per W
  constexpr int total = 4 * n4w;
  int i = blockIdx.x * 256 + threadIdx.x;
  for (; i < total; i += gridDim.x * 256) {
    int sg = i >> 18, off = i & (n4w - 1);
    const float* s = sg == 0 ? wq : sg == 1 ? wk : sg == 2 ? wv : wo;
    short* d       = sg == 0 ? dwq : sg == 1 ? dwk : sg == 2 ? dwv : dwo;
    float4 x = ((const float4*)s)[off];
    uint2 o;
    o.x = pk2bf(x.x, x.y);
    o.y = pk2bf(x.z, x.w);
    ((uint2*)d)[off] = o;
  }
}

constexpr float QSCALE = 0.18033688011112042f;  // 0.125 * log2(e)

// ---------------------------------------------------------------------------
// Fused QKV GEMM: C = (A_fp32 @ W_bf16^T + bias) * oscale.
// m97 structure; A staged as FP32 via global_load_lds (zero-VGPR staging,
// latency handled by the same barrier drain as the proven bf16 path) into a
// 16KB [128][32]f32 tile with pre-swizzled source cols (rule #21: linear
// LDS dest + src col ^ (row&7) in 16B units + XOR on read - fixes the
// 128B-row 16-way bank conflict). Fragments convert fp32->bf16 on read
// (2x ds_read_b128 + 4 pk2bf) - bit-identical operands to the old prepass.
// B (weights) unchanged: bf16 via gload_lds, linear 64B-row LDS.
// ---------------------------------------------------------------------------
__global__ __launch_bounds__(256)
void qkv_kernel(const float* __restrict__ q, const float* __restrict__ k,
                const float* __restrict__ v,
                const short* __restrict__ wq16, const short* __restrict__ wk16,
                const short* __restrict__ wv16,
                const float* __restrict__ bq, const float* __restrict__ bk,
                const float* __restrict__ bv,
                short* __restrict__ qh, short* __restrict__ kh,
                short* __restrict__ vt)
{
  const int z = blockIdx.z;
  const float* A = (z == 0) ? q : (z == 1) ? k : v;
  const short* W = (z == 0) ? wq16 : (z == 1) ? wk16 : wv16;
  const float* bias = (z == 0) ? bq : (z == 1) ? bk : bv;
  short* Cp = (z == 0) ? qh : (z == 1) ? kh : vt;
  const int mode = (z == 2) ? 2 : 0;
  const float oscale = (z == 0) ? QSCALE : 1.0f;
  const int m0 = blockIdx.x * 128, n0 = blockIdx.y * 128;

  __shared__ float Asf[128 * 32];    // fp32 A tile, 128B rows, swizzled
  __shared__ short Bs[128 * 32];
  const int t = threadIdx.x, lane = t & 63, w = t >> 6;
  const int wr = w >> 1, wc = w & 1, g = lane >> 4, l15 = lane & 15;

  f32x4 acc[4][4] = {};

  // B staging (bf16, gload_lds, linear)
  const int c0 = t, c1 = 256 + t;
  const short* gb0 = W + (size_t)(n0 + (c0 >> 2)) * 1024 + ((c0 & 3) << 3);
  const short* gb1 = W + (size_t)(n0 + (c1 >> 2)) * 1024 + ((c1 & 3) << 3);
  short* lb0 = &Bs[(w * 64) * 8];
  short* lb1 = &Bs[(256 + w * 64) * 8];

  // A staging (fp32, gload_lds): chunk c = j*256 + t, row = c>>3,
  // 16B-unit u = c&7; source col pre-swizzled: u' = u ^ (row&7).
  const float* gaA[4];
  #pragma unroll
  for (int j = 0; j < 4; ++j) {
    int c = j * 256 + t;
    int row = c >> 3, u = (c & 7) ^ (row & 7);
    gaA[j] = A + (size_t)(m0 + row) * 1024 + u * 4;
  }
  float* laA[4];
  #pragma unroll
  for (int j = 0; j < 4; ++j)
    laA[j] = &Asf[(j * 256 + w * 64) * 4];   // wave-uniform, lane*16B linear

  for (int k0 = 0; k0 < 1024; k0 += 32) {
    __syncthreads();
    gload16(gaA[0] + k0, laA[0]);
    gload16(gaA[1] + k0, laA[1]);
    gload16(gaA[2] + k0, laA[2]);
    gload16(gaA[3] + k0, laA[3]);
    gload16(gb0 + k0, lb0);
    gload16(gb1 + k0, lb1);
    __syncthreads();

    bf16x8 af[4], bfr[4];
    #pragma unroll
    for (int m = 0; m < 4; ++m) {
      int row = wr * 64 + m * 16 + l15;
      int sw = (row & 7) << 4;
      const char* base = (const char*)Asf;
      f32x4 lo = *(const f32x4*)(base + ((row * 128 + g * 32) ^ sw));
      f32x4 hi = *(const f32x4*)(base + ((row * 128 + g * 32 + 16) ^ sw));
      u32x4 aw = {pk2bf(lo[0], lo[1]), pk2bf(lo[2], lo[3]),
                  pk2bf(hi[0], hi[1]), pk2bf(hi[2], hi[3])};
      af[m] = __builtin_bit_cast(bf16x8, aw);
    }
    #pragma unroll
    for (int n = 0; n < 4; ++n)
      bfr[n] = *(const bf16x8*)&Bs[(wc * 64 + n * 16 + l15) * 32 + g * 8];
    #pragma unroll
    for (int m = 0; m < 4; ++m)
      #pragma unroll
      for (int n = 0; n < 4; ++n)
        acc[m][n] = mfma16(af[m], bfr[n], acc[m][n]);
  }

  // C/D: col = lane&15, row = (lane>>4)*4 + reg  [m89]
  #pragma unroll
  for (int n = 0; n < 4; ++n) {
    int ng = n0 + wc * 64 + n * 16 + l15;
    float bv = bias[ng];
    #pragma unroll
    for (int m = 0; m < 4; ++m) {
      int mb = m0 + wr * 64 + m * 16 + g * 4;
      #pragma unroll
      for (int r = 0; r < 4; ++r) {
        int mg = mb + r;
        float val = (acc[m][n][r] + bv) * oscale;
        int b = mg >> 11, srow = mg & 2047;
        int h = ng >> 6,  dh   = ng & 63;
        if (mode == 0)
          ((short*)Cp)[(((size_t)b * HH + h) * SS + srow) * DHD + dh] = f2bf(val);
        else
          ((short*)Cp)[(((size_t)b * HH + h) * DHD + dh) * SS + srow] = f2bf(val);
      }
    }
  }
}

// ---------------------------------------------------------------------------
// Output projection: m97-structure GEMM (all-bf16, single-buffered).
// ---------------------------------------------------------------------------
__global__ __launch_bounds__(256)
void proj_kernel(const short* __restrict__ ao, const short* __restrict__ wo16,
                 const float* __restrict__ bo, float* __restrict__ out)
{
  const int m0 = blockIdx.x * 128, n0 = blockIdx.y * 128;
  __shared__ short As[128 * 32];
  __shared__ short Bs[128 * 32];
  const int t = threadIdx.x, lane = t & 63, w = t >> 6;
  const int wr = w >> 1, wc = w & 1, g = lane >> 4, l15 = lane & 15;

  f32x4 acc[4][4] = {};

  const int c0 = t, c1 = 256 + t;
  const short* ga0 = ao + (size_t)(m0 + (c0 >> 2)) * 1024 + ((c0 & 3) << 3);
  const short* ga1 = ao + (size_t)(m0 + (c1 >> 2)) * 1024 + ((c1 & 3) << 3);
  const short* gb0 = wo16 + (size_t)(n0 + (c0 >> 2)) * 1024 + ((c0 & 3) << 3);
  const short* gb1 = wo16 + (size_t)(n0 + (c1 >> 2)) * 1024 + ((c1 & 3) << 3);
  short* la0 = &As[(w * 64) * 8];
  short* la1 = &As[(256 + w * 64) * 8];
  short* lb0 = &Bs[(w * 64) * 8];
  short* lb1 = &Bs[(256 + w * 64) * 8];

  for (int k0 = 0; k0 < 1024; k0 += 32) {
    __syncthreads();
    gload16(ga0 + k0, la0);
    gload16(ga1 + k0, la1);
    gload16(gb0 + k0, lb0);
    gload16(gb1 + k0, lb1);
    __syncthreads();

    bf16x8 af[4], bfr[4];
    #pragma unroll
    for (int m = 0; m < 4; ++m)
      af[m] = *(const bf16x8*)&As[(wr * 64 + m * 16 + l15) * 32 + g * 8];
    #pragma unroll
    for (int n = 0; n < 4; ++n)
      bfr[n] = *(const bf16x8*)&Bs[(wc * 64 + n * 16 + l15) * 32 + g * 8];
    #pragma unroll
    for (int m = 0; m < 4; ++m)
      #pragma unroll
      for (int n = 0; n < 4; ++n)
        acc[m][n] = mfma16(af[m], bfr[n], acc[m][n]);
  }

  #pragma unroll
  for (int n = 0; n < 4; ++n) {
    int ng = n0 + wc * 64 + n * 16 + l15;
    float bv = bo[ng];
    #pragma unroll
    for (int m = 0; m < 4; ++m) {
      int mb = m0 + wr * 64 + m * 16 + g * 4;
      #pragma unroll
      for (int r = 0; r < 4; ++r)
        out[(size_t)(mb + r) * 1024 + ng] = acc[m][n][r] + bv;
    }
  }
}

// ---------------------------------------------------------------------------
// Flash attention (r15/r20 verbatim - best measured, 48.0us): sequential
// paired q-tiles, uniform 17 staged-tile units/block, 512 blocks = 2/CU,
// swapped QK, no-max exp2 softmax, permlane P-transpose, XOR-swizzled
// reg-staged K/V, T5 setprio.
// ---------------------------------------------------------------------------
__global__ __launch_bounds__(256)
void attn_kernel(const short* __restrict__ qh, const short* __restrict__ kh,
                 const short* __restrict__ vt, short* __restrict__ out)
{
  __shared__ short Ks[128 * 64];     // [kv=128][d=64], swz byte^=(row&7)<<4
  __shared__ short Vs[64 * 128];     // [d=64][kv=128], swz byte^=(row&15)<<4

  const int wg = blockIdx.x;
  const int s  = wg >> 3;
  const int bh = (wg & 7) * 4 + (s & 3);      // 4 heads per XCD
  const int p  = s >> 2;                      // pair index 0..15

  const int t = threadIdx.x, lane = t & 63, w = t >> 6;
  const int g = lane >> 4, l15 = lane & 15;
  const int b = bh >> 4, h = bh & 15;

  const short* kbh = kh + (size_t)bh * SS * DHD;
  const short* vbh = vt + (size_t)bh * DHD * SS;

  bf16x8 kr[4], vr[4];
  auto issue = [&](int k0) {
    #pragma unroll
    for (int j = 0; j < 4; ++j) {
      int c = j * 256 + t;
      kr[j] = *(const bf16x8*)(kbh + (size_t)(k0 + (c >> 3)) * DHD + ((c & 7) << 3));
      vr[j] = *(const bf16x8*)(vbh + (size_t)(c >> 4) * SS + k0 + ((c & 15) << 3));
    }
  };
  auto commit = [&]() {
    #pragma unroll
    for (int j = 0; j < 4; ++j) {
      int c = j * 256 + t;
      int kb_ = ((c >> 3) * 128 + (c & 7) * 16) ^ (((c >> 3) & 7) << 4);
      int vb_ = ((c >> 4) * 256 + (c & 15) * 16) ^ (((c >> 4) & 15) << 4);
      *(bf16x8*)((char*)Ks + kb_) = kr[j];
      *(bf16x8*)((char*)Vs + vb_) = vr[j];
    }
  };

  #pragma unroll 1
  for (int ph = 0; ph < 2; ++ph) {
    const int y = ph ? (31 - p) : p;
    const int ktiles = (y + 2) >> 1;          // 128-wide kv tiles

    const short* qp = qh + ((size_t)bh * SS + y * 64 + w * 16 + l15) * DHD + g * 8;
    bf16x8 q0f = *(const bf16x8*)(qp);
    bf16x8 q1f = *(const bf16x8*)(qp + 32);

    f32x4 o[4] = {};
    f32x4 lv = {0.f, 0.f, 0.f, 0.f};
    const int qg = y * 64 + w * 16 + l15;

    issue(0);
    for (int kt = 0; kt < ktiles; ++kt) {
      const int k0 = kt * 128;
      __syncthreads();                // prev compute done, buffers free
      commit();                       // vmcnt wait + swizzled ds_write
      __syncthreads();                // tile staged
      if (kt + 1 < ktiles) issue(k0 + 128);  // next tile flies under compute

      f32x4 s4[8];
      __builtin_amdgcn_s_setprio(1);
      #pragma unroll
      for (int nk = 0; nk < 8; ++nk) {
        int row = nk * 16 + l15;
        int sw = (row & 7) << 4;
        bf16x8 kf0 = *(const bf16x8*)((const char*)Ks + ((row * 128 + g * 16) ^ sw));
        bf16x8 kf1 = *(const bf16x8*)((const char*)Ks + ((row * 128 + 64 + g * 16) ^ sw));
        f32x4 z = {0.f, 0.f, 0.f, 0.f};
        z = mfma16(kf0, q0f, z);
        s4[nk] = mfma16(kf1, q1f, z);
      }
      __builtin_amdgcn_s_setprio(0);
      if (kt == ktiles - 1) {         // only the last tile crosses the diagonal
        #pragma unroll
        for (int nk = 0; nk < 8; ++nk)
          #pragma unroll
          for (int r = 0; r < 4; ++r)
            if (k0 + nk * 16 + g * 4 + r > qg) s4[nk][r] = -__builtin_inff();
      }
      #pragma unroll
      for (int nk = 0; nk < 8; ++nk) {
        #pragma unroll
        for (int r = 0; r < 4; ++r) s4[nk][r] = exp2f(s4[nk][r]);
        lv += s4[nk];
      }
      __builtin_amdgcn_s_setprio(1);
      #pragma unroll
      for (int i = 0; i < 4; ++i) {
        uint32_t w0 = pk2bf(s4[2 * i][0], s4[2 * i][1]);
        uint32_t w1 = pk2bf(s4[2 * i][2], s4[2 * i][3]);
        uint32_t w2 = pk2bf(s4[2 * i + 1][0], s4[2 * i + 1][1]);
        uint32_t w3 = pk2bf(s4[2 * i + 1][2], s4[2 * i + 1][3]);
        auto p1 = __builtin_amdgcn_permlane32_swap(w0, w2, false, false);
        auto p2 = __builtin_amdgcn_permlane16_swap(p1[0], p1[1], false, false);
        auto p3 = __builtin_amdgcn_permlane32_swap(w1, w3, false, false);
        auto p4 = __builtin_amdgcn_permlane16_swap(p3[0], p3[1], false, false);
        u32x4 paw = {(unsigned)p2[0], (unsigned)p4[0],
                     (unsigned)p2[1], (unsigned)p4[1]};
        bf16x8 pa = __builtin_bit_cast(bf16x8, paw);
        #pragma unroll
        for (int nd = 0; nd < 4; ++nd) {
          int row = nd * 16 + l15;
          int byt = (row * 256 + i * 64 + g * 16) ^ ((row & 15) << 4);
          bf16x8 vf = *(const bf16x8*)((const char*)Vs + byt);
          o[nd] = mfma16(pa, vf, o[nd]);
        }
      }
      __builtin_amdgcn_s_setprio(0);
    }

    float l = (lv[0] + lv[1]) + (lv[2] + lv[3]);
    l += __shfl_xor(l, 16, 64);
    l += __shfl_xor(l, 32, 64);
    #pragma unroll
    for (int r = 0; r < 4; ++r) {
      float lr = __shfl(l, g * 4 + r, 64);
      float inv = 1.0f / lr;
      int srow = y * 64 + w * 16 + g * 4 + r;
      #pragma unroll
      for (int nd = 0; nd < 4; ++nd) {
        int dcol = h * 64 + nd * 16 + l15;
        out[((size_t)b * SS + srow) * DD + dcol] = f2bf(o[nd][r] * inv);
      }
    }
  }
}

// ---------------------------------------------------------------------------
extern "C" void kernel_launch(void* const* d_in, const int* in_sizes, int n_in,
                              void* d_out, int out_size, void* d_ws, size_t ws_size,
                              hipStream_t stream) {
  (void)in_sizes; (void)n_in; (void)out_size; (void)ws_size;
  const float* q  = (const float*)d_in[0];
  const float* k  = (const float*)d_in[1];
  const float* v  = (const float*)d_in[2];
  // d_in[3] = causal mask (statically triu(k=1)) applied analytically
  const float* Wq = (const float*)d_in[4];
  const float* bq = (const float*)d_in[5];
  const float* Wk = (const float*)d_in[6];
  const float* bk = (const float*)d_in[7];
  const float* Wv = (const float*)d_in[8];
  const float* bv = (const float*)d_in[9];
  const float* Wo = (const float*)d_in[10];
  const float* bo = (const float*)d_in[11];

  constexpr size_t NTOK = (size_t)MTOK * DD;     // 4M elements
  constexpr size_t NW   = (size_t)DD * DD;       // 1M elements
  short* wq16 = (short*)d_ws;                    // [1024,1024] bf16 x4
  short* wk16 = wq16 + NW;
  short* wv16 = wk16 + NW;
  short* wo16 = wv16 + NW;
  short* qh   = wo16 + NW;                       // [B,H,S,DH] bf16 (pre-scaled)
  short* kh   = qh + NTOK;                       // [B,H,S,DH] bf16
  short* vt   = kh + NTOK;                       // [B,H,DH,S] bf16
  short* ao   = vt + NTOK;                       // [B,S,D]   bf16

  dim3 blk(256);
  cvtw_kernel<<<dim3(512), blk, 0, stream>>>(Wq, Wk, Wv, Wo,
                                             wq16, wk16, wv16, wo16);
  qkv_kernel<<<dim3(MTOK / 128, DD / 128, 3), blk, 0, stream>>>(
      q, k, v, wq16, wk16, wv16, bq, bk, bv, qh, kh, vt);
  attn_kernel<<<dim3(512), blk, 0, stream>>>(qh, kh, vt, ao);
  proj_kernel<<<dim3(MTOK / 128, DD / 128), blk, 0, stream>>>(ao, wo16, bo,
                                                              (float*)d_out);
}